// Round 2
// baseline (151.766 us; speedup 1.0000x reference)
//
#include <hip/hip_runtime.h>

using f32x4 = __attribute__((ext_vector_type(4))) float;
using s16x8 = __attribute__((ext_vector_type(8))) short;

static __device__ __forceinline__ unsigned short f2bf(float f){
  union { float f; unsigned int i; } c; c.f = f;
  return (unsigned short)((c.i + 0x7FFFu + ((c.i >> 16) & 1u)) >> 16);
}
static __device__ __forceinline__ s16x8 ld8(const unsigned short* p){
  return *(const s16x8*)p;
}
// 8 contiguous f32 -> bf16x8 frag (two float4 loads)
static __device__ __forceinline__ s16x8 cvt8(const float* p){
  const float4* q = (const float4*)p;
  float4 a = q[0], b = q[1];
  s16x8 r;
  r[0]=(short)f2bf(a.x); r[1]=(short)f2bf(a.y); r[2]=(short)f2bf(a.z); r[3]=(short)f2bf(a.w);
  r[4]=(short)f2bf(b.x); r[5]=(short)f2bf(b.y); r[6]=(short)f2bf(b.z); r[7]=(short)f2bf(b.w);
  return r;
}
static __device__ __forceinline__ f32x4 mfma16(s16x8 a, s16x8 b, f32x4 c){
  return __builtin_amdgcn_mfma_f32_16x16x32_bf16(a, b, c, 0, 0, 0);
}

// ---------------- rel_table[51] = sigmoid(relu(Eemb[d]@Wr1+br1)@Wr2), exact f32 ----------------
__global__ __launch_bounds__(64) void k_prep(const float* __restrict__ Ee,
    const float* __restrict__ Wr1, const float* __restrict__ br1,
    const float* __restrict__ Wr2, float* __restrict__ rel_t)
{
  int t = threadIdx.x;
  if (t < 51){
    float e[32];
    for (int j = 0; j < 32; ++j) e[j] = Ee[t*32 + j];
    float w = 0.f;
    for (int h = 0; h < 16; ++h){
      float s = br1[h];
      for (int j = 0; j < 32; ++j) s += e[j] * Wr1[j*16 + h];
      s = fmaxf(s, 0.f);
      w += s * Wr2[h];
    }
    rel_t[t] = 1.f / (1.f + __expf(-w));
  }
}

// ---------------- xp = x @ Wp + bp  (8192x256 @ 256x64), f32 in, bf16 out ----------------
__global__ __launch_bounds__(256) void k_xp(const float* __restrict__ x,
    const float* __restrict__ Wp, const float* __restrict__ bp,
    unsigned short* __restrict__ xp)
{
  __shared__ __align__(16) unsigned short Wt[64*264];   // Wp^T [n][k] bf16, pad 256->264
  int t = threadIdx.x;
  for (int i = t; i < 256*64; i += 256){
    int k = i >> 6, n = i & 63;
    Wt[n*264 + k] = f2bf(Wp[i]);
  }
  __syncthreads();
  int lane = t & 63, wave = t >> 6;
  int colL = lane & 15, quad = lane >> 4;
  int row0 = blockIdx.x * 64 + wave * 16;
  const float* xr = x + (row0 + colL)*256;
  f32x4 acc[4] = {};
  for (int kc = 0; kc < 256; kc += 32){
    s16x8 a = cvt8(xr + kc + quad*8);
#pragma unroll
    for (int nt = 0; nt < 4; ++nt){
      s16x8 b = ld8(&Wt[(nt*16 + colL)*264 + kc + quad*8]);
      acc[nt] = mfma16(a, b, acc[nt]);
    }
  }
#pragma unroll
  for (int nt = 0; nt < 4; ++nt){
    int col = nt*16 + colL;
    float bias = bp[col];
#pragma unroll
    for (int i = 0; i < 4; ++i){
      int row = row0 + quad*4 + i;
      xp[row*64 + col] = f2bf(acc[nt][i] + bias);
    }
  }
}

// ---------------- q/k/v = xp @ W* + b*  (v stored transposed per batch: vt[b][d][m]) ----------------
__global__ __launch_bounds__(256) void k_qkv(const unsigned short* __restrict__ xp,
    const float* __restrict__ Wq, const float* __restrict__ bq,
    const float* __restrict__ Wk, const float* __restrict__ bk,
    const float* __restrict__ Wv, const float* __restrict__ bv,
    unsigned short* __restrict__ q, unsigned short* __restrict__ k, unsigned short* __restrict__ vt)
{
  int which = blockIdx.y;
  const float* W    = which==0 ? Wq : (which==1 ? Wk : Wv);
  const float* bias = which==0 ? bq : (which==1 ? bk : bv);
  __shared__ __align__(16) unsigned short Wt[64*72];    // W^T [n][k] bf16, pad 64->72
  int t = threadIdx.x;
  for (int i = t; i < 64*64; i += 256){
    int kx = i >> 6, n = i & 63;
    Wt[n*72 + kx] = f2bf(W[i]);
  }
  __syncthreads();
  int lane = t & 63, wave = t >> 6;
  int colL = lane & 15, quad = lane >> 4;
  int row0 = blockIdx.x*64 + wave*16;
  f32x4 acc[4] = {};
#pragma unroll
  for (int kc = 0; kc < 64; kc += 32){
    s16x8 a = ld8(xp + (row0+colL)*64 + kc + quad*8);
#pragma unroll
    for (int nt = 0; nt < 4; ++nt){
      s16x8 b = ld8(&Wt[(nt*16+colL)*72 + kc + quad*8]);
      acc[nt] = mfma16(a, b, acc[nt]);
    }
  }
#pragma unroll
  for (int nt = 0; nt < 4; ++nt){
    int col = nt*16 + colL;
    float bb = bias[col];
#pragma unroll
    for (int i = 0; i < 4; ++i){
      int row = row0 + quad*4 + i;
      float v = acc[nt][i] + bb;
      if (which == 0)      q[row*64 + col] = f2bf(v);
      else if (which == 1) k[row*64 + col] = f2bf(v);
      else                 vt[(row>>9)*32768 + col*512 + (row & 511)] = f2bf(v);
    }
  }
}

// ---------------- attention: S=qk^T/8 * rel[dist], softmax, O=P@v ----------------
__global__ __launch_bounds__(128) void k_attn(const unsigned short* __restrict__ q,
    const unsigned short* __restrict__ kmat, const unsigned short* __restrict__ vt,
    const int* __restrict__ ranks, const float* __restrict__ rel_t,
    unsigned short* __restrict__ ao)
{
  int b = blockIdx.y, qb = blockIdx.x;
  int t = threadIdx.x;
  int lane = t & 63, wave = t >> 6;
  int colL = lane & 15, quad = lane >> 4;

  __shared__ int r_s[512];
  __shared__ float rt_s[64];
  __shared__ __align__(16) unsigned short P[2][16*520];  // per-wave P, pad 512->520

  for (int i = t; i < 512; i += 128) r_s[i] = ranks[b*512 + i];
  if (t < 64) rt_s[t] = (t < 51) ? rel_t[t] : 0.f;
  __syncthreads();

  int row0 = qb*32 + wave*16;                     // q-row tile within batch
  const unsigned short* qp = q    + b*512*64;
  const unsigned short* kp = kmat + b*512*64;
  const unsigned short* vp = vt   + b*64*512;

  s16x8 aq0 = ld8(qp + (row0+colL)*64 +  0 + quad*8);
  s16x8 aq1 = ld8(qp + (row0+colL)*64 + 32 + quad*8);

  f32x4 S[32];
#pragma unroll
  for (int mt = 0; mt < 32; ++mt){
    s16x8 b0 = ld8(kp + (mt*16+colL)*64 +  0 + quad*8);
    s16x8 b1 = ld8(kp + (mt*16+colL)*64 + 32 + quad*8);
    f32x4 c = {};
    c = mfma16(aq0, b0, c);
    c = mfma16(aq1, b1, c);
    S[mt] = c;
  }

  int rq[4];
#pragma unroll
  for (int i = 0; i < 4; ++i) rq[i] = r_s[row0 + quad*4 + i];

  float rmax[4] = {-1e30f,-1e30f,-1e30f,-1e30f};
#pragma unroll
  for (int mt = 0; mt < 32; ++mt){
    int rm = r_s[mt*16 + colL];
#pragma unroll
    for (int i = 0; i < 4; ++i){
      int dd = rq[i] - rm; dd = dd < 0 ? -dd : dd; dd = dd > 50 ? 50 : dd;
      float s = S[mt][i] * 0.125f * rt_s[dd];
      S[mt][i] = s;
      rmax[i] = fmaxf(rmax[i], s);
    }
  }
#pragma unroll
  for (int i = 0; i < 4; ++i){
    rmax[i] = fmaxf(rmax[i], __shfl_xor(rmax[i], 1));
    rmax[i] = fmaxf(rmax[i], __shfl_xor(rmax[i], 2));
    rmax[i] = fmaxf(rmax[i], __shfl_xor(rmax[i], 4));
    rmax[i] = fmaxf(rmax[i], __shfl_xor(rmax[i], 8));
  }
  float rsum[4] = {0.f,0.f,0.f,0.f};
#pragma unroll
  for (int mt = 0; mt < 32; ++mt){
#pragma unroll
    for (int i = 0; i < 4; ++i){
      float p = __expf(S[mt][i] - rmax[i]);
      S[mt][i] = p;
      rsum[i] += p;
    }
  }
#pragma unroll
  for (int i = 0; i < 4; ++i){
    rsum[i] += __shfl_xor(rsum[i], 1);
    rsum[i] += __shfl_xor(rsum[i], 2);
    rsum[i] += __shfl_xor(rsum[i], 4);
    rsum[i] += __shfl_xor(rsum[i], 8);
  }
  float inv[4];
#pragma unroll
  for (int i = 0; i < 4; ++i) inv[i] = 1.f / rsum[i];

  unsigned short* Pw = P[wave];
#pragma unroll
  for (int mt = 0; mt < 32; ++mt){
#pragma unroll
    for (int i = 0; i < 4; ++i)
      Pw[(quad*4+i)*520 + mt*16 + colL] = f2bf(S[mt][i] * inv[i]);
  }
  __syncthreads();

  f32x4 O[4] = {};
#pragma unroll
  for (int mc = 0; mc < 512; mc += 32){
    s16x8 ap = ld8(&Pw[colL*520 + mc + quad*8]);
#pragma unroll
    for (int dt = 0; dt < 4; ++dt){
      s16x8 bb = ld8(vp + (dt*16+colL)*512 + mc + quad*8);
      O[dt] = mfma16(ap, bb, O[dt]);
    }
  }
#pragma unroll
  for (int dt = 0; dt < 4; ++dt){
#pragma unroll
    for (int i = 0; i < 4; ++i)
      ao[(b*512 + row0 + quad*4 + i)*64 + dt*16 + colL] = f2bf(O[dt][i]);
  }
}

// ---------------- FFN + LayerNorm + score head, fused; f32 weights, f32 out ----------------
__global__ __launch_bounds__(256) void k_ffn(const unsigned short* __restrict__ ao,
    const float* __restrict__ Wf1, const float* __restrict__ bf1,
    const float* __restrict__ Wf2, const float* __restrict__ bf2,
    const float* __restrict__ lng, const float* __restrict__ lnb,
    const float* __restrict__ Ws1, const float* __restrict__ bs1,
    const float* __restrict__ Ws2, const float* __restrict__ bs2,
    float* __restrict__ out)
{
  __shared__ __align__(16) unsigned short Wf1t[128*72];   // [n=128][k=64+pad]
  __shared__ __align__(16) unsigned short Wf2t[64*136];   // [n=64][k=128+pad]
  __shared__ __align__(16) unsigned short Ws1t[32*72];    // [n=32][k=64+pad]
  __shared__ __align__(16) unsigned short hbuf[4][16*136];// per-wave h1 (then reused for hn)
  __shared__ float cb[384];  // 0:bf1[128] 128:bf2[64] 192:g[64] 256:b[64] 320:bs1[32] 352:Ws2[32]

  int t = threadIdx.x;
  for (int i = t; i < 64*128; i += 256){ int d = i>>7, j = i&127; Wf1t[j*72 + d] = f2bf(Wf1[i]); }
  for (int i = t; i < 128*64; i += 256){ int kx = i>>6, n = i&63; Wf2t[n*136 + kx] = f2bf(Wf2[i]); }
  for (int i = t; i < 64*32;  i += 256){ int d = i>>5, c = i&31; Ws1t[c*72 + d] = f2bf(Ws1[i]); }
  if (t < 128) cb[t] = bf1[t];
  if (t < 64){ cb[128+t] = bf2[t]; cb[192+t] = lng[t]; cb[256+t] = lnb[t]; }
  if (t < 32){ cb[320+t] = bs1[t]; cb[352+t] = Ws2[t]; }
  __syncthreads();

  int lane = t & 63, wave = t >> 6, colL = lane & 15, quad = lane >> 4;
  int row0 = blockIdx.x*64 + wave*16;
  unsigned short* hw = hbuf[wave];

  // GEMM1: h1 = relu(ao@Wf1 + bf1), 16x128 per wave
  f32x4 a1[8] = {};
#pragma unroll
  for (int kc = 0; kc < 64; kc += 32){
    s16x8 a = ld8(ao + (row0+colL)*64 + kc + quad*8);
#pragma unroll
    for (int nt = 0; nt < 8; ++nt){
      s16x8 b = ld8(&Wf1t[(nt*16+colL)*72 + kc + quad*8]);
      a1[nt] = mfma16(a, b, a1[nt]);
    }
  }
#pragma unroll
  for (int nt = 0; nt < 8; ++nt){
    int col = nt*16 + colL;
    float bb = cb[col];
#pragma unroll
    for (int i = 0; i < 4; ++i)
      hw[(quad*4+i)*136 + col] = f2bf(fmaxf(a1[nt][i] + bb, 0.f));
  }
  __syncthreads();

  // GEMM2: h = h1@Wf2 + bf2, then LayerNorm
  f32x4 a2[4] = {};
#pragma unroll
  for (int kc = 0; kc < 128; kc += 32){
    s16x8 a = ld8(&hw[colL*136 + kc + quad*8]);
#pragma unroll
    for (int nt = 0; nt < 4; ++nt){
      s16x8 b = ld8(&Wf2t[(nt*16+colL)*136 + kc + quad*8]);
      a2[nt] = mfma16(a, b, a2[nt]);
    }
  }
  float vals[4][4];
#pragma unroll
  for (int nt = 0; nt < 4; ++nt){
    float bb = cb[128 + nt*16 + colL];
#pragma unroll
    for (int i = 0; i < 4; ++i) vals[i][nt] = a2[nt][i] + bb;
  }
  __syncthreads();  // all waves done reading h1 before hbuf is rewritten as hn

  float hnv[4][4];
#pragma unroll
  for (int i = 0; i < 4; ++i){
    float s = vals[i][0]+vals[i][1]+vals[i][2]+vals[i][3];
    s += __shfl_xor(s,1); s += __shfl_xor(s,2); s += __shfl_xor(s,4); s += __shfl_xor(s,8);
    float mu = s * (1.f/64.f);
    float d0=vals[i][0]-mu, d1=vals[i][1]-mu, d2=vals[i][2]-mu, d3=vals[i][3]-mu;
    float s2 = d0*d0 + d1*d1 + d2*d2 + d3*d3;
    s2 += __shfl_xor(s2,1); s2 += __shfl_xor(s2,2); s2 += __shfl_xor(s2,4); s2 += __shfl_xor(s2,8);
    float invs = rsqrtf(s2*(1.f/64.f) + 1e-5f);
#pragma unroll
    for (int nt = 0; nt < 4; ++nt){
      int col = nt*16 + colL;
      hnv[i][nt] = (vals[i][nt]-mu)*invs*cb[192+col] + cb[256+col];
    }
  }
#pragma unroll
  for (int i = 0; i < 4; ++i)
#pragma unroll
    for (int nt = 0; nt < 4; ++nt)
      hw[(quad*4+i)*72 + nt*16 + colL] = f2bf(hnv[i][nt]);
  __syncthreads();

  // GEMM3: s1 = relu(hn@Ws1 + bs1); out = sigmoid(s1@Ws2 + bs2)
  f32x4 a3[2] = {};
#pragma unroll
  for (int kc = 0; kc < 64; kc += 32){
    s16x8 a = ld8(&hw[colL*72 + kc + quad*8]);
#pragma unroll
    for (int nt = 0; nt < 2; ++nt){
      s16x8 b = ld8(&Ws1t[(nt*16+colL)*72 + kc + quad*8]);
      a3[nt] = mfma16(a, b, a3[nt]);
    }
  }
  float bs2f = bs2[0];
#pragma unroll
  for (int i = 0; i < 4; ++i){
    float p = 0.f;
#pragma unroll
    for (int nt = 0; nt < 2; ++nt){
      int col = nt*16 + colL;
      p += fmaxf(a3[nt][i] + cb[320+col], 0.f) * cb[352+col];
    }
    p += __shfl_xor(p,1); p += __shfl_xor(p,2); p += __shfl_xor(p,4); p += __shfl_xor(p,8);
    if (colL == 0){
      float z = p + bs2f;
      out[row0 + quad*4 + i] = 1.f / (1.f + __expf(-z));
    }
  }
}

extern "C" void kernel_launch(void* const* d_in, const int* in_sizes, int n_in,
                              void* d_out, int out_size, void* d_ws, size_t ws_size,
                              hipStream_t stream)
{
  const float* x    = (const float*)d_in[0];
  const int*   rank = (const int*)d_in[1];
  const float* Wp   = (const float*)d_in[2];
  const float* bp   = (const float*)d_in[3];
  const float* Wq   = (const float*)d_in[4];
  const float* bq   = (const float*)d_in[5];
  const float* Wk   = (const float*)d_in[6];
  const float* bk   = (const float*)d_in[7];
  const float* Wv   = (const float*)d_in[8];
  const float* bv   = (const float*)d_in[9];
  const float* Ee   = (const float*)d_in[10];
  const float* Wr1  = (const float*)d_in[11];
  const float* br1  = (const float*)d_in[12];
  const float* Wr2  = (const float*)d_in[13];
  const float* Wf1  = (const float*)d_in[14];
  const float* bf1  = (const float*)d_in[15];
  const float* Wf2  = (const float*)d_in[16];
  const float* bf2  = (const float*)d_in[17];
  const float* lng  = (const float*)d_in[18];
  const float* lnb  = (const float*)d_in[19];
  const float* Ws1  = (const float*)d_in[20];
  const float* bs1  = (const float*)d_in[21];
  const float* Ws2  = (const float*)d_in[22];
  const float* bs2  = (const float*)d_in[23];
  float* out = (float*)d_out;

  char* ws = (char*)d_ws;
  float*          rel_t = (float*)(ws + 0);
  unsigned short* xp    = (unsigned short*)(ws + 256);
  unsigned short* q     = (unsigned short*)(ws + 256 + 1*1048576);
  unsigned short* kk    = (unsigned short*)(ws + 256 + 2*1048576);
  unsigned short* vt    = (unsigned short*)(ws + 256 + 3*1048576);
  unsigned short* ao    = (unsigned short*)(ws + 256 + 4*1048576);

  k_prep<<<dim3(1), dim3(64), 0, stream>>>(Ee, Wr1, br1, Wr2, rel_t);
  k_xp<<<dim3(128), dim3(256), 0, stream>>>(x, Wp, bp, xp);
  k_qkv<<<dim3(128, 3), dim3(256), 0, stream>>>(xp, Wq, bq, Wk, bk, Wv, bv, q, kk, vt);
  k_attn<<<dim3(16, 16), dim3(128), 0, stream>>>(q, kk, vt, rank, rel_t, ao);
  k_ffn<<<dim3(128), dim3(256), 0, stream>>>(ao, Wf1, bf1, Wf2, bf2, lng, lnb,
                                             Ws1, bs1, Ws2, bs2, out);
}

// Round 3
// 147.327 us; speedup vs baseline: 1.0301x; 1.0301x over previous
//
#include <hip/hip_runtime.h>

using f32x4 = __attribute__((ext_vector_type(4))) float;
using s16x8 = __attribute__((ext_vector_type(8))) short;

static __device__ __forceinline__ unsigned short f2bf(float f){
  union { float f; unsigned int i; } c; c.f = f;
  return (unsigned short)((c.i + 0x7FFFu + ((c.i >> 16) & 1u)) >> 16);
}
static __device__ __forceinline__ s16x8 ld8(const unsigned short* p){
  return *(const s16x8*)p;
}
static __device__ __forceinline__ s16x8 cvt8(const float* p){
  const float4* q = (const float4*)p;
  float4 a = q[0], b = q[1];
  s16x8 r;
  r[0]=(short)f2bf(a.x); r[1]=(short)f2bf(a.y); r[2]=(short)f2bf(a.z); r[3]=(short)f2bf(a.w);
  r[4]=(short)f2bf(b.x); r[5]=(short)f2bf(b.y); r[6]=(short)f2bf(b.z); r[7]=(short)f2bf(b.w);
  return r;
}
static __device__ __forceinline__ f32x4 mfma16(s16x8 a, s16x8 b, f32x4 c){
  return __builtin_amdgcn_mfma_f32_16x16x32_bf16(a, b, c, 0, 0, 0);
}

// ============ k_proj: x -> xp (LDS) -> q,k,vt; block 0 also builds rel_t ============
// grid 256 x 128thr; block owns 32 rows (2 waves x 16)
__global__ __launch_bounds__(128) void k_proj(const float* __restrict__ x,
    const float* __restrict__ Wp, const float* __restrict__ bp,
    const float* __restrict__ Wq, const float* __restrict__ bq,
    const float* __restrict__ Wk, const float* __restrict__ bk,
    const float* __restrict__ Wv, const float* __restrict__ bv,
    const float* __restrict__ Ee, const float* __restrict__ Wr1,
    const float* __restrict__ br1, const float* __restrict__ Wr2,
    unsigned short* __restrict__ q, unsigned short* __restrict__ kk,
    unsigned short* __restrict__ vt, float* __restrict__ rel_t)
{
  __shared__ __align__(16) unsigned short WpT[64*264];   // Wp^T [n][k], 264*2=528B: 16B-aligned rows
  __shared__ __align__(16) unsigned short Wt3[3][64*72]; // Wq/Wk/Wv^T [n][k]
  __shared__ __align__(16) unsigned short xs[2][16*72];  // per-wave xp tile

  int t = threadIdx.x;
  // stage Wp^T (each thread owns column n=t&63, walks k)
  for (int i = t; i < 256*64; i += 128){
    int k = i >> 6, n = i & 63;
    WpT[n*264 + k] = f2bf(Wp[i]);
  }
  for (int i = t; i < 64*64; i += 128){
    int k2 = i >> 6, n = i & 63;
    Wt3[0][n*72 + k2] = f2bf(Wq[i]);
    Wt3[1][n*72 + k2] = f2bf(Wk[i]);
    Wt3[2][n*72 + k2] = f2bf(Wv[i]);
  }
  // rel table (block 0 only; overlapped with other blocks' work)
  if (blockIdx.x == 0 && t < 51){
    float e[32];
    for (int j = 0; j < 32; ++j) e[j] = Ee[t*32 + j];
    float w = 0.f;
    for (int h = 0; h < 16; ++h){
      float s = br1[h];
      for (int j = 0; j < 32; ++j) s += e[j] * Wr1[j*16 + h];
      w += fmaxf(s, 0.f) * Wr2[h];
    }
    rel_t[t] = 1.f / (1.f + __expf(-w));
  }
  __syncthreads();

  int lane = t & 63, wave = t >> 6, colL = lane & 15, quad = lane >> 4;
  int row0 = blockIdx.x*32 + wave*16;

  // xp = x @ Wp + bp (16x64 per wave), kept in own-wave LDS
  const float* xr = x + (row0 + colL)*256;
  f32x4 acc[4] = {};
  for (int kc = 0; kc < 256; kc += 32){
    s16x8 a = cvt8(xr + kc + quad*8);
#pragma unroll
    for (int nt = 0; nt < 4; ++nt)
      acc[nt] = mfma16(a, ld8(&WpT[(nt*16+colL)*264 + kc + quad*8]), acc[nt]);
  }
  unsigned short* xw = xs[wave];
#pragma unroll
  for (int nt = 0; nt < 4; ++nt){
    int col = nt*16 + colL;
    float bb = bp[col];
#pragma unroll
    for (int i = 0; i < 4; ++i)
      xw[(quad*4+i)*72 + col] = f2bf(acc[nt][i] + bb);
  }
  // own-wave LDS write->read: compiler inserts lgkmcnt wait; no barrier needed
  s16x8 a0 = ld8(&xw[colL*72 +  0 + quad*8]);
  s16x8 a1 = ld8(&xw[colL*72 + 32 + quad*8]);

#pragma unroll
  for (int w = 0; w < 3; ++w){
    const float* bias = w==0 ? bq : (w==1 ? bk : bv);
    f32x4 c[4] = {};
#pragma unroll
    for (int nt = 0; nt < 4; ++nt){
      c[nt] = mfma16(a0, ld8(&Wt3[w][(nt*16+colL)*72 +  0 + quad*8]), c[nt]);
      c[nt] = mfma16(a1, ld8(&Wt3[w][(nt*16+colL)*72 + 32 + quad*8]), c[nt]);
    }
#pragma unroll
    for (int nt = 0; nt < 4; ++nt){
      int col = nt*16 + colL;
      float bb = bias[col];
#pragma unroll
      for (int i = 0; i < 4; ++i){
        int row = row0 + quad*4 + i;
        float v = c[nt][i] + bb;
        if (w == 0)      q [row*64 + col] = f2bf(v);
        else if (w == 1) kk[row*64 + col] = f2bf(v);
        else             vt[(row>>9)*32768 + col*512 + (row & 511)] = f2bf(v);
      }
    }
  }
}

// ============ k_attn: 4-way key-split flash block ============
// grid (32 qtiles, 16 batches) x 256thr; wave w owns keys [w*128,(w+1)*128)
__global__ __launch_bounds__(256) void k_attn(const unsigned short* __restrict__ q,
    const unsigned short* __restrict__ kmat, const unsigned short* __restrict__ vt,
    const int* __restrict__ ranks, const float* __restrict__ rel_t,
    unsigned short* __restrict__ ao)
{
  int b = blockIdx.y, qt = blockIdx.x;
  int t = threadIdx.x, lane = t & 63, wave = t >> 6;
  int colL = lane & 15, quad = lane >> 4;

  __shared__ int r_s[512];
  __shared__ float rt_s[64];
  __shared__ __align__(16) unsigned short P[4][16*136]; // per-wave P (128 keys, pad->136)
  __shared__ float Opart[4][16*66];
  __shared__ float pmax_s[4][16], psum_s[4][16];

  for (int i = t; i < 512; i += 256) r_s[i] = ranks[b*512 + i];
  if (t < 64) rt_s[t] = (t < 51) ? rel_t[t] : 0.f;
  __syncthreads();

  int qrow0 = qt*16;
  const unsigned short* qp = q    + b*32768;
  const unsigned short* kp = kmat + b*32768;
  const unsigned short* vp = vt   + b*32768;

  s16x8 aq0 = ld8(qp + (qrow0+colL)*64 +  0 + quad*8);
  s16x8 aq1 = ld8(qp + (qrow0+colL)*64 + 32 + quad*8);

  int key0 = wave*128;
  f32x4 S[8];
#pragma unroll
  for (int mt = 0; mt < 8; ++mt){
    int key = key0 + mt*16 + colL;
    f32x4 c = {};
    c = mfma16(aq0, ld8(kp + key*64 +  0 + quad*8), c);
    c = mfma16(aq1, ld8(kp + key*64 + 32 + quad*8), c);
    S[mt] = c;
  }

  int rq[4];
#pragma unroll
  for (int i = 0; i < 4; ++i) rq[i] = r_s[qrow0 + quad*4 + i];

  float rmax[4] = {-1e30f,-1e30f,-1e30f,-1e30f};
#pragma unroll
  for (int mt = 0; mt < 8; ++mt){
    int rm = r_s[key0 + mt*16 + colL];
#pragma unroll
    for (int i = 0; i < 4; ++i){
      int dd = rq[i] - rm; dd = dd < 0 ? -dd : dd; dd = dd > 50 ? 50 : dd;
      float s = S[mt][i] * 0.125f * rt_s[dd];
      S[mt][i] = s;
      rmax[i] = fmaxf(rmax[i], s);
    }
  }
#pragma unroll
  for (int i = 0; i < 4; ++i){
    rmax[i] = fmaxf(rmax[i], __shfl_xor(rmax[i], 1));
    rmax[i] = fmaxf(rmax[i], __shfl_xor(rmax[i], 2));
    rmax[i] = fmaxf(rmax[i], __shfl_xor(rmax[i], 4));
    rmax[i] = fmaxf(rmax[i], __shfl_xor(rmax[i], 8));
  }
  if (colL == 0){
#pragma unroll
    for (int i = 0; i < 4; ++i) pmax_s[wave][quad*4 + i] = rmax[i];
  }
  __syncthreads();
  float gmax[4];
#pragma unroll
  for (int i = 0; i < 4; ++i){
    int r = quad*4 + i;
    gmax[i] = fmaxf(fmaxf(pmax_s[0][r], pmax_s[1][r]), fmaxf(pmax_s[2][r], pmax_s[3][r]));
  }
  float rsum[4] = {0.f,0.f,0.f,0.f};
#pragma unroll
  for (int mt = 0; mt < 8; ++mt){
#pragma unroll
    for (int i = 0; i < 4; ++i){
      float p = __expf(S[mt][i] - gmax[i]);
      S[mt][i] = p;
      rsum[i] += p;
    }
  }
#pragma unroll
  for (int i = 0; i < 4; ++i){
    rsum[i] += __shfl_xor(rsum[i], 1);
    rsum[i] += __shfl_xor(rsum[i], 2);
    rsum[i] += __shfl_xor(rsum[i], 4);
    rsum[i] += __shfl_xor(rsum[i], 8);
  }
  if (colL == 0){
#pragma unroll
    for (int i = 0; i < 4; ++i) psum_s[wave][quad*4 + i] = rsum[i];
  }
  __syncthreads();
  float inv[4];
#pragma unroll
  for (int i = 0; i < 4; ++i){
    int r = quad*4 + i;
    inv[i] = 1.f / (psum_s[0][r] + psum_s[1][r] + psum_s[2][r] + psum_s[3][r]);
  }
  unsigned short* Pw = P[wave];
#pragma unroll
  for (int mt = 0; mt < 8; ++mt){
#pragma unroll
    for (int i = 0; i < 4; ++i)
      Pw[(quad*4+i)*136 + mt*16 + colL] = f2bf(S[mt][i] * inv[i]);
  }
  // PV on own-wave P (no barrier needed)
  f32x4 O[4] = {};
#pragma unroll
  for (int mc = 0; mc < 128; mc += 32){
    s16x8 ap = ld8(&Pw[colL*136 + mc + quad*8]);
#pragma unroll
    for (int dt = 0; dt < 4; ++dt)
      O[dt] = mfma16(ap, ld8(vp + (dt*16+colL)*512 + key0 + mc + quad*8), O[dt]);
  }
  float* Ow = Opart[wave];
#pragma unroll
  for (int dt = 0; dt < 4; ++dt)
#pragma unroll
    for (int i = 0; i < 4; ++i)
      Ow[(quad*4+i)*66 + dt*16 + colL] = O[dt][i];
  __syncthreads();
  for (int e = t; e < 1024; e += 256){
    int row = e >> 6, col = e & 63;
    float s = Opart[0][row*66+col] + Opart[1][row*66+col]
            + Opart[2][row*66+col] + Opart[3][row*66+col];
    ao[(b*512 + qrow0 + row)*64 + col] = f2bf(s);
  }
}

// ============ k_ffn: FFN + LayerNorm + head; grid 256 x 128thr (32 rows/block) ============
__global__ __launch_bounds__(128) void k_ffn(const unsigned short* __restrict__ ao,
    const float* __restrict__ Wf1, const float* __restrict__ bf1,
    const float* __restrict__ Wf2, const float* __restrict__ bf2,
    const float* __restrict__ lng, const float* __restrict__ lnb,
    const float* __restrict__ Ws1, const float* __restrict__ bs1,
    const float* __restrict__ Ws2, const float* __restrict__ bs2,
    float* __restrict__ out)
{
  __shared__ __align__(16) unsigned short Wf1t[128*72];
  __shared__ __align__(16) unsigned short Wf2t[64*136];
  __shared__ __align__(16) unsigned short Ws1t[32*72];
  __shared__ __align__(16) unsigned short hbuf[2][16*136];
  __shared__ float cb[384];

  int t = threadIdx.x;
  for (int i = t; i < 64*128; i += 128){ int d = i>>7, j = i&127; Wf1t[j*72 + d] = f2bf(Wf1[i]); }
  for (int i = t; i < 128*64; i += 128){ int kx = i>>6, n = i&63; Wf2t[n*136 + kx] = f2bf(Wf2[i]); }
  for (int i = t; i < 64*32;  i += 128){ int d = i>>5, c = i&31; Ws1t[c*72 + d] = f2bf(Ws1[i]); }
  if (t < 128) cb[t] = bf1[t];
  if (t < 64){ cb[128+t] = bf2[t]; cb[192+t] = lng[t]; cb[256+t] = lnb[t]; }
  if (t < 32){ cb[320+t] = bs1[t]; cb[352+t] = Ws2[t]; }
  __syncthreads();

  int lane = t & 63, wave = t >> 6, colL = lane & 15, quad = lane >> 4;
  int row0 = blockIdx.x*32 + wave*16;
  unsigned short* hw = hbuf[wave];

  // GEMM1: h1 = relu(ao@Wf1 + bf1)
  f32x4 a1[8] = {};
#pragma unroll
  for (int kc = 0; kc < 64; kc += 32){
    s16x8 a = ld8(ao + (row0+colL)*64 + kc + quad*8);
#pragma unroll
    for (int nt = 0; nt < 8; ++nt)
      a1[nt] = mfma16(a, ld8(&Wf1t[(nt*16+colL)*72 + kc + quad*8]), a1[nt]);
  }
#pragma unroll
  for (int nt = 0; nt < 8; ++nt){
    int col = nt*16 + colL;
    float bb = cb[col];
#pragma unroll
    for (int i = 0; i < 4; ++i)
      hw[(quad*4+i)*136 + col] = f2bf(fmaxf(a1[nt][i] + bb, 0.f));
  }
  // own-wave h1 -> GEMM2 (no barrier: hbuf is per-wave)
  f32x4 a2[4] = {};
#pragma unroll
  for (int kc = 0; kc < 128; kc += 32){
    s16x8 a = ld8(&hw[colL*136 + kc + quad*8]);
#pragma unroll
    for (int nt = 0; nt < 4; ++nt)
      a2[nt] = mfma16(a, ld8(&Wf2t[(nt*16+colL)*136 + kc + quad*8]), a2[nt]);
  }
  float vals[4][4];
#pragma unroll
  for (int nt = 0; nt < 4; ++nt){
    float bb = cb[128 + nt*16 + colL];
#pragma unroll
    for (int i = 0; i < 4; ++i) vals[i][nt] = a2[nt][i] + bb;
  }
  float hnv[4][4];
#pragma unroll
  for (int i = 0; i < 4; ++i){
    float s = vals[i][0]+vals[i][1]+vals[i][2]+vals[i][3];
    s += __shfl_xor(s,1); s += __shfl_xor(s,2); s += __shfl_xor(s,4); s += __shfl_xor(s,8);
    float mu = s * (1.f/64.f);
    float d0=vals[i][0]-mu, d1=vals[i][1]-mu, d2=vals[i][2]-mu, d3=vals[i][3]-mu;
    float s2 = d0*d0 + d1*d1 + d2*d2 + d3*d3;
    s2 += __shfl_xor(s2,1); s2 += __shfl_xor(s2,2); s2 += __shfl_xor(s2,4); s2 += __shfl_xor(s2,8);
    float invs = rsqrtf(s2*(1.f/64.f) + 1e-5f);
#pragma unroll
    for (int nt = 0; nt < 4; ++nt){
      int col = nt*16 + colL;
      hnv[i][nt] = (vals[i][nt]-mu)*invs*cb[192+col] + cb[256+col];
    }
  }
#pragma unroll
  for (int i = 0; i < 4; ++i)
#pragma unroll
    for (int nt = 0; nt < 4; ++nt)
      hw[(quad*4+i)*72 + nt*16 + colL] = f2bf(hnv[i][nt]);

  f32x4 a3[2] = {};
#pragma unroll
  for (int kc = 0; kc < 64; kc += 32){
    s16x8 a = ld8(&hw[colL*72 + kc + quad*8]);
#pragma unroll
    for (int nt = 0; nt < 2; ++nt)
      a3[nt] = mfma16(a, ld8(&Ws1t[(nt*16+colL)*72 + kc + quad*8]), a3[nt]);
  }
  float bs2f = bs2[0];
#pragma unroll
  for (int i = 0; i < 4; ++i){
    float p = 0.f;
#pragma unroll
    for (int nt = 0; nt < 2; ++nt){
      int col = nt*16 + colL;
      p += fmaxf(a3[nt][i] + cb[320+col], 0.f) * cb[352+col];
    }
    p += __shfl_xor(p,1); p += __shfl_xor(p,2); p += __shfl_xor(p,4); p += __shfl_xor(p,8);
    if (colL == 0){
      float z = p + bs2f;
      out[row0 + quad*4 + i] = 1.f / (1.f + __expf(-z));
    }
  }
}

extern "C" void kernel_launch(void* const* d_in, const int* in_sizes, int n_in,
                              void* d_out, int out_size, void* d_ws, size_t ws_size,
                              hipStream_t stream)
{
  const float* x    = (const float*)d_in[0];
  const int*   rank = (const int*)d_in[1];
  const float* Wp   = (const float*)d_in[2];
  const float* bp   = (const float*)d_in[3];
  const float* Wq   = (const float*)d_in[4];
  const float* bq   = (const float*)d_in[5];
  const float* Wk   = (const float*)d_in[6];
  const float* bk   = (const float*)d_in[7];
  const float* Wv   = (const float*)d_in[8];
  const float* bv   = (const float*)d_in[9];
  const float* Ee   = (const float*)d_in[10];
  const float* Wr1  = (const float*)d_in[11];
  const float* br1  = (const float*)d_in[12];
  const float* Wr2  = (const float*)d_in[13];
  const float* Wf1  = (const float*)d_in[14];
  const float* bf1  = (const float*)d_in[15];
  const float* Wf2  = (const float*)d_in[16];
  const float* bf2  = (const float*)d_in[17];
  const float* lng  = (const float*)d_in[18];
  const float* lnb  = (const float*)d_in[19];
  const float* Ws1  = (const float*)d_in[20];
  const float* bs1  = (const float*)d_in[21];
  const float* Ws2  = (const float*)d_in[22];
  const float* bs2  = (const float*)d_in[23];
  float* out = (float*)d_out;

  char* ws = (char*)d_ws;
  float*          rel_t = (float*)(ws + 0);
  unsigned short* q     = (unsigned short*)(ws + 256);
  unsigned short* kk    = (unsigned short*)(ws + 256 + 1*1048576);
  unsigned short* vt    = (unsigned short*)(ws + 256 + 2*1048576);
  unsigned short* ao    = (unsigned short*)(ws + 256 + 3*1048576);

  k_proj<<<dim3(256), dim3(128), 0, stream>>>(x, Wp, bp, Wq, bq, Wk, bk, Wv, bv,
                                              Ee, Wr1, br1, Wr2, q, kk, vt, rel_t);
  k_attn<<<dim3(32, 16), dim3(256), 0, stream>>>(q, kk, vt, rank, rel_t, ao);
  k_ffn<<<dim3(256), dim3(128), 0, stream>>>(ao, Wf1, bf1, Wf2, bf2, lng, lnb,
                                             Ws1, bs1, Ws2, bs2, out);
}